// Round 1
// baseline (542.635 us; speedup 1.0000x reference)
//
#include <hip/hip_runtime.h>
#include <math.h>

#define HDIM 256
#define NATT 100

// ---------------------------------------------------------------------------
// prep: fold weights
//   wcm[h]  = sum_n Ws2[n]*Ws1[n,h]          (s chain collapse, M)
//   wcc[h]  = same for C
//   m2m[c,h]= sum_n Wd[c,n]*W2[n,h]          (W_2 -> W_d collapse, M)
//   m2c[c,h]= same for C
//   consts  = [b_combM, b_combC, bdm0, bdm1, bdc0, bdc1]
// ---------------------------------------------------------------------------
__launch_bounds__(256)
__global__ void prep_kernel(
    const float* __restrict__ Ws1, const float* __restrict__ bs1,
    const float* __restrict__ Ws2, const float* __restrict__ bs2,
    const float* __restrict__ Ws1C, const float* __restrict__ bs1C,
    const float* __restrict__ Ws2C, const float* __restrict__ bs2C,
    const float* __restrict__ W2,  const float* __restrict__ b2,
    const float* __restrict__ Wd,
    const float* __restrict__ W2C, const float* __restrict__ b2C,
    const float* __restrict__ WdC,
    float* __restrict__ wcm, float* __restrict__ wcc,
    float* __restrict__ m2m, float* __restrict__ m2c,
    float* __restrict__ consts)
{
    const int h = threadIdx.x;
    const int blk = blockIdx.x;
    if (blk == 0) {
        float a = 0.f;
        for (int k = 0; k < HDIM; ++k) a += Ws2[k] * Ws1[k*HDIM + h];
        wcm[h] = a;
        if (h == 0) {
            float bsum = bs2[0];
            for (int k = 0; k < HDIM; ++k) bsum += Ws2[k] * bs1[k];
            consts[0] = bsum;
        }
    } else if (blk == 1) {
        float a = 0.f;
        for (int k = 0; k < HDIM; ++k) a += Ws2C[k] * Ws1C[k*HDIM + h];
        wcc[h] = a;
        if (h == 0) {
            float bsum = bs2C[0];
            for (int k = 0; k < HDIM; ++k) bsum += Ws2C[k] * bs1C[k];
            consts[1] = bsum;
        }
    } else if (blk < 4) {
        const int c = blk - 2;
        float a = 0.f;
        for (int k = 0; k < HDIM; ++k) a += Wd[c*HDIM + k] * W2[k*HDIM + h];
        m2m[c*HDIM + h] = a;
        if (h == 0) {
            float bsum = 0.f;
            for (int k = 0; k < HDIM; ++k) bsum += Wd[c*HDIM + k] * b2[k];
            consts[2 + c] = bsum;
        }
    } else {
        const int c = blk - 4;
        float a = 0.f;
        for (int k = 0; k < HDIM; ++k) a += WdC[c*HDIM + k] * W2C[k*HDIM + h];
        m2c[c*HDIM + h] = a;
        if (h == 0) {
            float bsum = 0.f;
            for (int k = 0; k < HDIM; ++k) bsum += WdC[c*HDIM + k] * b2C[k];
            consts[4 + c] = bsum;
        }
    }
}

// ---------------------------------------------------------------------------
// main: one block per scene (8 objects, 64 ordered pairs p = i*8+j)
// produces: pm[b,64], s_raw[b,64], sC_raw[b,64], unit vecs u_mass/u_charge
//           per-token (2 floats), block partial sums for batchnorm stats
// ---------------------------------------------------------------------------
__launch_bounds__(256, 2)
__global__ void main_kernel(
    const float* __restrict__ z_dyn, const float* __restrict__ z_contex,
    const float* __restrict__ z_mc,
    const float* __restrict__ W_e,  const float* __restrict__ b_e,
    const float* __restrict__ W_i,  const float* __restrict__ b_i,
    const float* __restrict__ W_a,  const float* __restrict__ b_a,
    const float* __restrict__ W_at, const float* __restrict__ b_at,
    const float* __restrict__ W_at2,const float* __restrict__ b_at2,
    const float* __restrict__ W_eC, const float* __restrict__ b_eC,
    const float* __restrict__ W_iC, const float* __restrict__ b_iC,
    const float* __restrict__ wcm,  const float* __restrict__ wcc,
    const float* __restrict__ m2m,  const float* __restrict__ m2c,
    const float* __restrict__ consts,
    float* __restrict__ pm_g, float* __restrict__ s_g, float* __restrict__ sC_g,
    float* __restrict__ um_g, float* __restrict__ uc_g, float* __restrict__ part_g)
{
    // LDS (~58 KB -> 2 blocks/CU)
    __shared__ float s_in[8][16];                   // per obj: [zd0,zd1, zc0..11, zm, zc]
    alignas(16) __shared__ float proj[16][260];     // rows 0..7: j-part, 8..15: i-part
    alignas(16) __shared__ float Wt[NATT][36];      // W_at K-chunk
    alignas(16) __shared__ float Aemb[64][36];      // A_emb K-chunk
    __shared__ float pm_s[64];
    __shared__ float pmsum_s[8];
    __shared__ float ss_s[64];
    __shared__ float sc_s[64];
    alignas(16) __shared__ float AccE[8][260];
    alignas(16) __shared__ float AccC[8][260];
    __shared__ float y_s[32];

    const int tid = threadIdx.x;
    const int b = blockIdx.x;

    // ---- Ph0: load scene inputs ----
    if (tid < 128) {
        const int o = tid >> 4, c = tid & 15;
        const int tok = b*8 + o;
        float v;
        if (c < 2)       v = z_dyn[tok*2 + c];
        else if (c < 14) v = z_contex[tok*12 + (c-2)];
        else             v = z_mc[tok*2 + (c-14)];
        s_in[o][c] = v;
    }
    __syncthreads();

    // ---- Ph1: A projections (x_12 layout: cols 0..13 = cd_j, 14..27 = cd_i) ----
    {
        const int h = tid;
        float w[28];
        #pragma unroll
        for (int k = 0; k < 28; ++k) w[k] = W_a[h*28 + k];
        #pragma unroll
        for (int o = 0; o < 8; ++o) {
            float pj = 0.f, pi = 0.f;
            #pragma unroll
            for (int k = 0; k < 14; ++k) {
                const float x = s_in[o][k];
                pj += w[k]    * x;
                pi += w[14+k] * x;
            }
            proj[o][h]   = pj;
            proj[8+o][h] = pi;
        }
    }
    __syncthreads();

    // ---- Ph2: presents = sigmoid(W_at2 @ tanh(W_at @ A_emb + b_at) + b_at2) ----
    // chunk-K GEMM: M=64 pairs, N=100, K=256; thread owns 4 pairs x 7 a-outputs
    float acc[4][7];
    #pragma unroll
    for (int pp = 0; pp < 4; ++pp)
        #pragma unroll
        for (int m = 0; m < 7; ++m) acc[pp][m] = 0.f;

    const int pg = tid >> 4;        // 16 pair-groups
    const int lA = tid & 15;        // 16 a-lanes
    const int p0 = pg * 4;

    for (int k0 = 0; k0 < 256; k0 += 32) {
        for (int idx = tid; idx < NATT*32; idx += 256) {
            const int r = idx >> 5, c = idx & 31;
            Wt[r][c] = W_at[r*256 + k0 + c];
        }
        for (int idx = tid; idx < 64*32; idx += 256) {
            const int p = idx >> 5, c = idx & 31;
            const int i = p >> 3, j = p & 7;
            const float v = proj[j][k0+c] + proj[8+i][k0+c] + b_a[k0+c];
            Aemb[p][c] = fmaxf(v, 0.f);
        }
        __syncthreads();
        #pragma unroll
        for (int kq = 0; kq < 8; ++kq) {
            const float4 x0 = *(const float4*)&Aemb[p0+0][kq*4];
            const float4 x1 = *(const float4*)&Aemb[p0+1][kq*4];
            const float4 x2 = *(const float4*)&Aemb[p0+2][kq*4];
            const float4 x3 = *(const float4*)&Aemb[p0+3][kq*4];
            #pragma unroll
            for (int m = 0; m < 7; ++m) {
                const int a = lA*7 + m;
                if (a < NATT) {
                    const float4 w = *(const float4*)&Wt[a][kq*4];
                    acc[0][m] += x0.x*w.x + x0.y*w.y + x0.z*w.z + x0.w*w.w;
                    acc[1][m] += x1.x*w.x + x1.y*w.y + x1.z*w.z + x1.w*w.w;
                    acc[2][m] += x2.x*w.x + x2.y*w.y + x2.z*w.z + x2.w*w.w;
                    acc[3][m] += x3.x*w.x + x3.y*w.y + x3.z*w.z + x3.w*w.w;
                }
            }
        }
        __syncthreads();
    }
    {
        float part[4];
        #pragma unroll
        for (int pp = 0; pp < 4; ++pp) {
            float s = 0.f;
            #pragma unroll
            for (int m = 0; m < 7; ++m) {
                const int a = lA*7 + m;
                if (a < NATT) s += W_at2[a] * tanhf(acc[pp][m] + b_at[a]);
            }
            s += __shfl_xor(s, 1); s += __shfl_xor(s, 2);
            s += __shfl_xor(s, 4); s += __shfl_xor(s, 8);
            part[pp] = s;
        }
        if (lA == 0) {
            #pragma unroll
            for (int pp = 0; pp < 4; ++pp) {
                const int p = p0 + pp;
                const int i = p >> 3, j = p & 7;
                const float logit = part[pp] + b_at2[0];
                const float pres = 1.f / (1.f + expf(-logit));
                const float pmv = (i != j) ? pres : 0.f;
                pm_s[p] = pmv;
                pm_g[b*64 + p] = pmv;
            }
        }
    }
    __syncthreads();
    if (tid < 8) {
        float su = 0.f;
        #pragma unroll
        for (int i = 0; i < 8; ++i) su += pm_s[i*8 + tid];
        pmsum_s[tid] = su;
    }

    // ---- Ph3a: I projections (f_12: col0=zm_j, 1..14=cd_j, 15=zm_i, 16..29=cd_i) ----
    {
        const int h = tid;
        float w[30];
        #pragma unroll
        for (int k = 0; k < 30; ++k) w[k] = W_i[h*30 + k];
        #pragma unroll
        for (int o = 0; o < 8; ++o) {
            const float zm = s_in[o][14];
            float pj = w[0]*zm, pi = w[15]*zm;
            #pragma unroll
            for (int k = 0; k < 14; ++k) {
                const float x = s_in[o][k];
                pj += w[1+k]  * x;
                pi += w[16+k] * x;
            }
            proj[o][h]   = pj;
            proj[8+o][h] = pi;
        }
    }
    __syncthreads();
    {   // s = dot(relu(I_emb), wcm) + b_combM   (4 lanes per pair)
        const int p = tid >> 2, l2 = tid & 3;
        const int i = p >> 3, j = p & 7;
        float a = 0.f;
        for (int h = l2; h < 256; h += 4) {
            const float e = fmaxf(proj[j][h] + proj[8+i][h] + b_i[h], 0.f);
            a += e * wcm[h];
        }
        a += __shfl_xor(a, 1); a += __shfl_xor(a, 2);
        if (l2 == 0) {
            const float sv = a + consts[0];
            ss_s[p] = sv;
            s_g[b*64 + p] = sv;
        }
    }
    __syncthreads();

    // ---- Ph3b: iC projections (fc_12: 0..11 ct_j, 12..23 ct_i, 24 zc_j, 25 zc_i,
    //                                   26..27 v_j, 28..29 v_i) ----
    {
        const int h = tid;
        float w[30];
        #pragma unroll
        for (int k = 0; k < 30; ++k) w[k] = W_iC[h*30 + k];
        #pragma unroll
        for (int o = 0; o < 8; ++o) {
            const float zc = s_in[o][15];
            const float v0 = s_in[o][0], v1 = s_in[o][1];
            float pj = w[24]*zc + w[26]*v0 + w[27]*v1;
            float pi = w[25]*zc + w[28]*v0 + w[29]*v1;
            #pragma unroll
            for (int k = 0; k < 12; ++k) {
                const float x = s_in[o][2+k];
                pj += w[k]    * x;
                pi += w[12+k] * x;
            }
            proj[o][h]   = pj;
            proj[8+o][h] = pi;
        }
    }
    __syncthreads();
    {
        const int p = tid >> 2, l2 = tid & 3;
        const int i = p >> 3, j = p & 7;
        float a = 0.f;
        for (int h = l2; h < 256; h += 4) {
            const float e = fmaxf(proj[j][h] + proj[8+i][h] + b_iC[h], 0.f);
            a += e * wcc[h];
        }
        a += __shfl_xor(a, 1); a += __shfl_xor(a, 2);
        if (l2 == 0) {
            const float sv = a + consts[1];
            sc_s[p] = sv;
            sC_g[b*64 + p] = sv;
        }
    }
    __syncthreads();

    // batchnorm partial sums (wave 0)
    if (tid < 64) {
        const float v1 = ss_s[tid], v2 = sc_s[tid];
        float a0 = v1, a1 = v1*v1, a2 = v2, a3 = v2*v2;
        #pragma unroll
        for (int m = 1; m < 64; m <<= 1) {
            a0 += __shfl_xor(a0, m); a1 += __shfl_xor(a1, m);
            a2 += __shfl_xor(a2, m); a3 += __shfl_xor(a3, m);
        }
        if (tid == 0) {
            part_g[b*4 + 0] = a0; part_g[b*4 + 1] = a1;
            part_g[b*4 + 2] = a2; part_g[b*4 + 3] = a3;
        }
    }

    // ---- Ph4a: E projections + pm-weighted accumulation over i ----
    {
        const int h = tid;
        float w[28];
        #pragma unroll
        for (int k = 0; k < 28; ++k) w[k] = W_e[h*28 + k];
        #pragma unroll
        for (int o = 0; o < 8; ++o) {
            float pj = 0.f, pi = 0.f;
            #pragma unroll
            for (int k = 0; k < 14; ++k) {
                const float x = s_in[o][k];
                pj += w[k]    * x;
                pi += w[14+k] * x;
            }
            proj[o][h]   = pj;
            proj[8+o][h] = pi;
        }
    }
    __syncthreads();
    {
        const int h = tid;
        const float be = b_e[h];
        float Pj[8], Pi[8];
        #pragma unroll
        for (int o = 0; o < 8; ++o) { Pj[o] = proj[o][h]; Pi[o] = proj[8+o][h]; }
        #pragma unroll
        for (int j = 0; j < 8; ++j) {
            float a = 0.f;
            #pragma unroll
            for (int i = 0; i < 8; ++i) {
                const float x = fmaxf(Pj[j] + Pi[i] + be, 0.f);
                a += pm_s[i*8 + j] * x;
            }
            AccE[j][h] = a;
        }
    }
    __syncthreads();

    // ---- Ph4b: eC projections + mask-weighted accumulation ----
    {
        const int h = tid;
        float w[30];
        #pragma unroll
        for (int k = 0; k < 30; ++k) w[k] = W_eC[h*30 + k];
        #pragma unroll
        for (int o = 0; o < 8; ++o) {
            const float zc = s_in[o][15];
            const float v0 = s_in[o][0], v1 = s_in[o][1];
            float pj = w[24]*zc + w[26]*v0 + w[27]*v1;
            float pi = w[25]*zc + w[28]*v0 + w[29]*v1;
            #pragma unroll
            for (int k = 0; k < 12; ++k) {
                const float x = s_in[o][2+k];
                pj += w[k]    * x;
                pi += w[12+k] * x;
            }
            proj[o][h]   = pj;
            proj[8+o][h] = pi;
        }
    }
    __syncthreads();
    {
        const int h = tid;
        const float be = b_eC[h];
        float Pj[8], Pi[8];
        #pragma unroll
        for (int o = 0; o < 8; ++o) { Pj[o] = proj[o][h]; Pi[o] = proj[8+o][h]; }
        #pragma unroll
        for (int j = 0; j < 8; ++j) {
            float a = 0.f;
            #pragma unroll
            for (int i = 0; i < 8; ++i) {
                const float x = fmaxf(Pj[j] + Pi[i] + be, 0.f);
                a += (i != j) ? x : 0.f;
            }
            AccC[j][h] = a;
        }
    }
    __syncthreads();

    // ---- Ph5: y = M2 @ Acc + pmsum*bd ; u = y / max(||y||,1e-12) ----
    {
        const int t = tid >> 3, l3 = tid & 7;        // 32 tasks x 8 lanes
        const int type = t >> 4, c = (t >> 3) & 1, j = t & 7;
        const float* M2 = type ? m2c : m2m;
        const float (*Acc)[260] = type ? AccC : AccE;
        float a = 0.f;
        for (int h = l3; h < 256; h += 8) a += M2[c*256 + h] * Acc[j][h];
        a += __shfl_xor(a, 1); a += __shfl_xor(a, 2); a += __shfl_xor(a, 4);
        if (l3 == 0) {
            const float bd = consts[2 + type*2 + c];
            const float pms = type ? 7.0f : pmsum_s[j];
            y_s[t] = a + pms * bd;
        }
    }
    __syncthreads();
    if (tid < 16) {
        const int type = tid >> 3, j = tid & 7;
        const float y0 = y_s[type*16 + j];
        const float y1 = y_s[type*16 + 8 + j];
        const float n = fmaxf(sqrtf(y0*y0 + y1*y1), 1e-12f);
        float* u = type ? uc_g : um_g;
        u[(b*8 + j)*2 + 0] = y0 / n;
        u[(b*8 + j)*2 + 1] = y1 / n;
    }
}

// ---------------------------------------------------------------------------
// stats: reduce 2048 block-partials -> kM,cM,kC,cC with normed = s*k + c
// ---------------------------------------------------------------------------
__launch_bounds__(256)
__global__ void stats_kernel(const float* __restrict__ part,
                             const float* __restrict__ gM, const float* __restrict__ beM,
                             const float* __restrict__ gC, const float* __restrict__ beC,
                             float* __restrict__ stats, int nblk, float inv_n)
{
    __shared__ float red[4][4];
    float a0 = 0.f, a1 = 0.f, a2 = 0.f, a3 = 0.f;
    for (int r = threadIdx.x; r < nblk; r += 256) {
        const float4 v = ((const float4*)part)[r];
        a0 += v.x; a1 += v.y; a2 += v.z; a3 += v.w;
    }
    #pragma unroll
    for (int m = 1; m < 64; m <<= 1) {
        a0 += __shfl_xor(a0, m); a1 += __shfl_xor(a1, m);
        a2 += __shfl_xor(a2, m); a3 += __shfl_xor(a3, m);
    }
    const int w = threadIdx.x >> 6;
    if ((threadIdx.x & 63) == 0) {
        red[0][w] = a0; red[1][w] = a1; red[2][w] = a2; red[3][w] = a3;
    }
    __syncthreads();
    if (threadIdx.x == 0) {
        float s = 0.f, s2 = 0.f, sc = 0.f, sc2 = 0.f;
        for (int k = 0; k < 4; ++k) {
            s += red[0][k]; s2 += red[1][k]; sc += red[2][k]; sc2 += red[3][k];
        }
        float mean = s * inv_n;
        float var  = s2 * inv_n - mean*mean;
        float kk   = gM[0] / sqrtf(var + 1e-5f);
        stats[0] = kk;
        stats[1] = beM[0] - mean*kk;
        mean = sc * inv_n;
        var  = sc2 * inv_n - mean*mean;
        kk   = gC[0] / sqrtf(var + 1e-5f);
        stats[2] = kk;
        stats[3] = beC[0] - mean*kk;
    }
}

// ---------------------------------------------------------------------------
// final: scale[b,j] = sum_i softplus(norm(s))*pm ; out = scale*u etc.
// out layout: [0:2N) = mass+charge, [2N:4N) = mass, [4N:6N) = charge
// ---------------------------------------------------------------------------
__launch_bounds__(256)
__global__ void final_kernel(const float* __restrict__ s_g, const float* __restrict__ sC_g,
                             const float* __restrict__ pm_g,
                             const float* __restrict__ um_g, const float* __restrict__ uc_g,
                             const float* __restrict__ stats,
                             float* __restrict__ out, int ntok)
{
    const int t = blockIdx.x * blockDim.x + threadIdx.x;
    if (t >= ntok) return;
    const int b = t >> 3, j = t & 7;
    const float kM = stats[0], cM = stats[1], kC = stats[2], cC = stats[3];
    float sc = 0.f, scC = 0.f;
    #pragma unroll
    for (int i = 0; i < 8; ++i) {
        const int idx = b*64 + i*8 + j;
        const float sn  = s_g[idx] * kM + cM;
        const float sp  = fmaxf(sn, 0.f) + log1pf(expf(-fabsf(sn)));
        sc += sp * pm_g[idx];
        const float snc = sC_g[idx] * kC + cC;
        const float spc = fmaxf(snc, 0.f) + log1pf(expf(-fabsf(snc)));
        scC += (i != j) ? spc : 0.f;
    }
    const float m0 = sc  * um_g[t*2],     m1 = sc  * um_g[t*2 + 1];
    const float c0 = scC * uc_g[t*2],     c1 = scC * uc_g[t*2 + 1];
    out[t*2]                 = m0 + c0;   out[t*2 + 1]             = m1 + c1;
    out[ntok*2 + t*2]        = m0;        out[ntok*2 + t*2 + 1]    = m1;
    out[ntok*4 + t*2]        = c0;        out[ntok*4 + t*2 + 1]    = c1;
}

extern "C" void kernel_launch(void* const* d_in, const int* in_sizes, int n_in,
                              void* d_out, int out_size, void* d_ws, size_t ws_size,
                              hipStream_t stream) {
    const float* z_dyn    = (const float*)d_in[0];
    const float* z_contex = (const float*)d_in[1];
    const float* z_mc     = (const float*)d_in[2];
    const float* W_e   = (const float*)d_in[3];  const float* b_e   = (const float*)d_in[4];
    const float* W_i   = (const float*)d_in[5];  const float* b_i   = (const float*)d_in[6];
    const float* W_a   = (const float*)d_in[7];  const float* b_a   = (const float*)d_in[8];
    const float* W_2   = (const float*)d_in[9];  const float* b_2   = (const float*)d_in[10];
    const float* W_at  = (const float*)d_in[11]; const float* b_at  = (const float*)d_in[12];
    const float* W_at2 = (const float*)d_in[13]; const float* b_at2 = (const float*)d_in[14];
    const float* W_s1  = (const float*)d_in[15]; const float* b_s1  = (const float*)d_in[16];
    const float* W_s2  = (const float*)d_in[17]; const float* b_s2  = (const float*)d_in[18];
    const float* W_eC  = (const float*)d_in[19]; const float* b_eC  = (const float*)d_in[20];
    const float* W_iC  = (const float*)d_in[21]; const float* b_iC  = (const float*)d_in[22];
    const float* W_2C  = (const float*)d_in[23]; const float* b_2C  = (const float*)d_in[24];
    const float* W_s1C = (const float*)d_in[25]; const float* b_s1C = (const float*)d_in[26];
    const float* W_s2C = (const float*)d_in[27]; const float* b_s2C = (const float*)d_in[28];
    const float* g_M   = (const float*)d_in[29]; const float* be_M  = (const float*)d_in[30];
    const float* g_C   = (const float*)d_in[31]; const float* be_C  = (const float*)d_in[32];
    const float* W_d   = (const float*)d_in[33];
    const float* W_dC  = (const float*)d_in[34];

    const int ntok = in_sizes[0] / 2;   // 16384
    const int B = ntok / 8;             // 2048

    float* ws = (float*)d_ws;
    float* pm_g   = ws;                  // B*64
    float* s_g    = pm_g + B*64;         // B*64
    float* sC_g   = s_g  + B*64;         // B*64
    float* um_g   = sC_g + B*64;         // ntok*2
    float* uc_g   = um_g + ntok*2;       // ntok*2
    float* part_g = uc_g + ntok*2;       // B*4
    float* wcm    = part_g + B*4;        // 256
    float* wcc    = wcm + 256;           // 256
    float* m2m    = wcc + 256;           // 512
    float* m2c    = m2m + 512;           // 512
    float* consts = m2c + 512;           // 8
    float* stats  = consts + 8;          // 4

    prep_kernel<<<6, 256, 0, stream>>>(
        W_s1, b_s1, W_s2, b_s2, W_s1C, b_s1C, W_s2C, b_s2C,
        W_2, b_2, W_d, W_2C, b_2C, W_dC,
        wcm, wcc, m2m, m2c, consts);

    main_kernel<<<B, 256, 0, stream>>>(
        z_dyn, z_contex, z_mc,
        W_e, b_e, W_i, b_i, W_a, b_a, W_at, b_at, W_at2, b_at2,
        W_eC, b_eC, W_iC, b_iC,
        wcm, wcc, m2m, m2c, consts,
        pm_g, s_g, sC_g, um_g, uc_g, part_g);

    stats_kernel<<<1, 256, 0, stream>>>(
        part_g, g_M, be_M, g_C, be_C, stats, B, 1.0f / (float)(B*64));

    final_kernel<<<(ntok + 255)/256, 256, 0, stream>>>(
        s_g, sC_g, pm_g, um_g, uc_g, stats, (float*)d_out, ntok);
}

// Round 2
// 353.719 us; speedup vs baseline: 1.5341x; 1.5341x over previous
//
#include <hip/hip_runtime.h>
#include <math.h>

#define HDIM 256
#define NATT 100
#define NPAD 112   // 7 col-tiles of 16

typedef __attribute__((ext_vector_type(8))) short short8v;
typedef __attribute__((ext_vector_type(4))) float f32x4;

static __device__ __forceinline__ unsigned short f2bf(float x) {
    union { float f; unsigned u; } v; v.f = x;
    const unsigned r = v.u + 0x7FFFu + ((v.u >> 16) & 1u);
    return (unsigned short)(r >> 16);
}
static __device__ __forceinline__ float bf2f(unsigned short s) {
    union { float f; unsigned u; } v; v.u = ((unsigned)s) << 16;
    return v.f;
}

// ---------------------------------------------------------------------------
// prep: fold weights + split W_at into bf16 hi/lo planes (padded to 112 rows)
//   wcm[h]  = sum_n Ws2[n]*Ws1[n,h]   (s chain collapse, M);  wcc = C version
//   m2m[c,h]= sum_n Wd[c,n]*W2[n,h]   (W_2 -> W_d collapse);  m2c = C version
//   consts  = [b_combM, b_combC, bdm0, bdm1, bdc0, bdc1]
// ---------------------------------------------------------------------------
__launch_bounds__(256)
__global__ void prep_kernel(
    const float* __restrict__ Ws1, const float* __restrict__ bs1,
    const float* __restrict__ Ws2, const float* __restrict__ bs2,
    const float* __restrict__ Ws1C, const float* __restrict__ bs1C,
    const float* __restrict__ Ws2C, const float* __restrict__ bs2C,
    const float* __restrict__ W2,  const float* __restrict__ b2,
    const float* __restrict__ Wd,
    const float* __restrict__ W2C, const float* __restrict__ b2C,
    const float* __restrict__ WdC,
    const float* __restrict__ W_at,
    float* __restrict__ wcm, float* __restrict__ wcc,
    float* __restrict__ m2m, float* __restrict__ m2c,
    float* __restrict__ consts,
    unsigned short* __restrict__ Wh, unsigned short* __restrict__ Wl)
{
    const int h = threadIdx.x;
    const int blk = blockIdx.x;
    if (blk == 0) {
        float a = 0.f;
        for (int k = 0; k < HDIM; ++k) a += Ws2[k] * Ws1[k*HDIM + h];
        wcm[h] = a;
        if (h == 0) {
            float bsum = bs2[0];
            for (int k = 0; k < HDIM; ++k) bsum += Ws2[k] * bs1[k];
            consts[0] = bsum;
        }
    } else if (blk == 1) {
        float a = 0.f;
        for (int k = 0; k < HDIM; ++k) a += Ws2C[k] * Ws1C[k*HDIM + h];
        wcc[h] = a;
        if (h == 0) {
            float bsum = bs2C[0];
            for (int k = 0; k < HDIM; ++k) bsum += Ws2C[k] * bs1C[k];
            consts[1] = bsum;
        }
    } else if (blk < 4) {
        const int c = blk - 2;
        float a = 0.f;
        for (int k = 0; k < HDIM; ++k) a += Wd[c*HDIM + k] * W2[k*HDIM + h];
        m2m[c*HDIM + h] = a;
        if (h == 0) {
            float bsum = 0.f;
            for (int k = 0; k < HDIM; ++k) bsum += Wd[c*HDIM + k] * b2[k];
            consts[2 + c] = bsum;
        }
    } else if (blk < 6) {
        const int c = blk - 4;
        float a = 0.f;
        for (int k = 0; k < HDIM; ++k) a += WdC[c*HDIM + k] * W2C[k*HDIM + h];
        m2c[c*HDIM + h] = a;
        if (h == 0) {
            float bsum = 0.f;
            for (int k = 0; k < HDIM; ++k) bsum += WdC[c*HDIM + k] * b2C[k];
            consts[4 + c] = bsum;
        }
    } else {
        // blocks 6..13: split W_at rows into bf16 hi/lo, zero-pad rows 100..111
        const int rbase = (blk - 6) * 14;
        for (int rr = 0; rr < 14; ++rr) {
            const int row = rbase + rr;
            const float v = (row < NATT) ? W_at[row*HDIM + h] : 0.f;
            const unsigned short hi = f2bf(v);
            Wh[row*HDIM + h] = hi;
            Wl[row*HDIM + h] = f2bf(v - bf2f(hi));
        }
    }
}

// ---------------------------------------------------------------------------
// main: one block (256 thr = 4 waves) per scene. Ph2 GEMM via split-bf16 MFMA.
// ---------------------------------------------------------------------------
__launch_bounds__(256, 4)
__global__ void main_kernel(
    const float* __restrict__ z_dyn, const float* __restrict__ z_contex,
    const float* __restrict__ z_mc,
    const float* __restrict__ W_e,  const float* __restrict__ b_e,
    const float* __restrict__ W_i,  const float* __restrict__ b_i,
    const float* __restrict__ W_a,  const float* __restrict__ b_a,
    const float* __restrict__ b_at,
    const float* __restrict__ W_at2,const float* __restrict__ b_at2,
    const float* __restrict__ W_eC, const float* __restrict__ b_eC,
    const float* __restrict__ W_iC, const float* __restrict__ b_iC,
    const unsigned short* __restrict__ Wh, const unsigned short* __restrict__ Wl,
    const float* __restrict__ wcm,  const float* __restrict__ wcc,
    const float* __restrict__ m2m,  const float* __restrict__ m2c,
    const float* __restrict__ consts,
    float* __restrict__ pm_g, float* __restrict__ s_g, float* __restrict__ sC_g,
    float* __restrict__ um_g, float* __restrict__ uc_g, float* __restrict__ part_g)
{
    __shared__ float s_in[8][16];                // per obj: [zd0,zd1, zc0..11, zm, zc]
    alignas(16) __shared__ float proj[16][260];  // rows 0..7: j-part, 8..15: i-part
    alignas(16) __shared__ float AccE[8][260];
    alignas(16) __shared__ float AccC[8][260];
    __shared__ float pm_t[64];                   // pm_t[j*8+i] = pm(i,j)
    __shared__ float pmsum_s[8];
    __shared__ float ss_s[64];
    __shared__ float sc_s[64];
    __shared__ float y_s[32];

    const int tid = threadIdx.x;
    const int b = blockIdx.x;

    // ---- Ph0: load scene inputs ----
    if (tid < 128) {
        const int o = tid >> 4, c = tid & 15;
        const int tok = b*8 + o;
        float v;
        if (c < 2)       v = z_dyn[tok*2 + c];
        else if (c < 14) v = z_contex[tok*12 + (c-2)];
        else             v = z_mc[tok*2 + (c-14)];
        s_in[o][c] = v;
    }
    __syncthreads();

    // ---- Ph1: A projections (x_12: cols 0..13 = cd_j, 14..27 = cd_i); 0.5*b_a folded
    {
        const int h = tid;
        float w[28];
        #pragma unroll
        for (int k = 0; k < 28; ++k) w[k] = W_a[h*28 + k];
        const float hb = 0.5f * b_a[h];
        #pragma unroll
        for (int o = 0; o < 8; ++o) {
            float pj = hb, pi = hb;
            #pragma unroll
            for (int k = 0; k < 14; ++k) {
                const float x = s_in[o][k];
                pj += w[k]    * x;
                pi += w[14+k] * x;
            }
            proj[o][h]   = pj;
            proj[8+o][h] = pi;
        }
    }
    __syncthreads();

    // ---- Ph2: presents GEMM (64x112x256) via split-bf16 MFMA, 3 passes ----
    {
        const int w    = tid >> 6;          // wave: rows 16w..16w+15 of D
        const int lane = tid & 63;
        const int lr   = lane & 15;         // A-row within tile / D-col
        const int lk   = lane >> 4;         // k-group
        const int pA = 16*w + lr;           // pair supplying this lane's A row
        const int jA = pA & 7, iA = pA >> 3;

        f32x4 acc[7];
        #pragma unroll
        for (int n = 0; n < 7; ++n) acc[n] = (f32x4){0.f, 0.f, 0.f, 0.f};

        #pragma unroll 2
        for (int k = 0; k < 8; ++k) {
            const int kb = k*32 + lk*8;     // 8 consecutive k per lane
            const float4 vj0 = *(const float4*)&proj[jA][kb];
            const float4 vj1 = *(const float4*)&proj[jA][kb+4];
            const float4 vi0 = *(const float4*)&proj[8+iA][kb];
            const float4 vi1 = *(const float4*)&proj[8+iA][kb+4];
            float v[8] = {vj0.x+vi0.x, vj0.y+vi0.y, vj0.z+vi0.z, vj0.w+vi0.w,
                          vj1.x+vi1.x, vj1.y+vi1.y, vj1.z+vi1.z, vj1.w+vi1.w};
            short8v ah, al;
            #pragma unroll
            for (int e = 0; e < 8; ++e) {
                const float r = fmaxf(v[e], 0.f);
                const unsigned short h16 = f2bf(r);
                ah[e] = (short)h16;
                al[e] = (short)f2bf(r - bf2f(h16));
            }
            #pragma unroll
            for (int n = 0; n < 7; ++n) {
                const int a = 16*n + lr;
                const short8v bh = *(const short8v*)&Wh[a*HDIM + kb];
                const short8v bl = *(const short8v*)&Wl[a*HDIM + kb];
                acc[n] = __builtin_amdgcn_mfma_f32_16x16x32_bf16(ah, bh, acc[n], 0, 0, 0);
                acc[n] = __builtin_amdgcn_mfma_f32_16x16x32_bf16(al, bh, acc[n], 0, 0, 0);
                acc[n] = __builtin_amdgcn_mfma_f32_16x16x32_bf16(ah, bl, acc[n], 0, 0, 0);
            }
        }

        // epilogue: s2 = sum_a W_at2[a]*tanh(D[p][a] + b_at[a]); sigmoid; mask
        float part[4] = {0.f, 0.f, 0.f, 0.f};
        #pragma unroll
        for (int n = 0; n < 7; ++n) {
            const int a = 16*n + lr;
            if (a < NATT) {
                const float bat = b_at[a], wat2 = W_at2[a];
                #pragma unroll
                for (int r = 0; r < 4; ++r)
                    part[r] += wat2 * tanhf(acc[n][r] + bat);
            }
        }
        #pragma unroll
        for (int r = 0; r < 4; ++r) {
            float s = part[r];
            s += __shfl_xor(s, 1); s += __shfl_xor(s, 2);
            s += __shfl_xor(s, 4); s += __shfl_xor(s, 8);
            part[r] = s;
        }
        if (lr == 0) {
            const float b2v = b_at2[0];
            #pragma unroll
            for (int r = 0; r < 4; ++r) {
                const int p = 16*w + 4*lk + r;      // D row = pair index
                const int ip = p >> 3, jp = p & 7;
                const float pres = 1.f / (1.f + expf(-(part[r] + b2v)));
                const float pmv = (ip != jp) ? pres : 0.f;
                pm_t[jp*8 + ip] = pmv;
                pm_g[b*64 + jp*8 + ip] = pmv;
            }
        }
    }
    __syncthreads();

    if (tid < 8) {
        float su = 0.f;
        #pragma unroll
        for (int i = 0; i < 8; ++i) su += pm_t[tid*8 + i];
        pmsum_s[tid] = su;
    }

    // ---- Ph3a: I projections (f_12: 0=zm_j,1..14=cd_j,15=zm_i,16..29=cd_i); 0.5*b_i folded
    {
        const int h = tid;
        float w[30];
        #pragma unroll
        for (int k = 0; k < 30; ++k) w[k] = W_i[h*30 + k];
        const float hb = 0.5f * b_i[h];
        #pragma unroll
        for (int o = 0; o < 8; ++o) {
            const float zm = s_in[o][14];
            float pj = hb + w[0]*zm, pi = hb + w[15]*zm;
            #pragma unroll
            for (int k = 0; k < 14; ++k) {
                const float x = s_in[o][k];
                pj += w[1+k]  * x;
                pi += w[16+k] * x;
            }
            proj[o][h]   = pj;
            proj[8+o][h] = pi;
        }
    }
    __syncthreads();
    {   // s = dot(relu(I_emb), wcm) + b_combM (4 lanes per pair, float4)
        const int p = tid >> 2, l2 = tid & 3;
        const int ip = p >> 3, jp = p & 7;
        float a = 0.f;
        #pragma unroll
        for (int u = 0; u < 16; ++u) {
            const int h4 = (l2*16 + u) * 4;
            const float4 aj = *(const float4*)&proj[jp][h4];
            const float4 ai = *(const float4*)&proj[8+ip][h4];
            const float4 wv = *(const float4*)&wcm[h4];
            a += wv.x*fmaxf(aj.x+ai.x, 0.f) + wv.y*fmaxf(aj.y+ai.y, 0.f)
               + wv.z*fmaxf(aj.z+ai.z, 0.f) + wv.w*fmaxf(aj.w+ai.w, 0.f);
        }
        a += __shfl_xor(a, 1); a += __shfl_xor(a, 2);
        if (l2 == 0) {
            const float sv = a + consts[0];
            ss_s[p] = sv;
            s_g[b*64 + jp*8 + ip] = sv;
        }
    }
    __syncthreads();

    // ---- Ph3b: iC projections (fc_12: 0..11 ct_j,12..23 ct_i,24 zc_j,25 zc_i,26..27 v_j,28..29 v_i)
    {
        const int h = tid;
        float w[30];
        #pragma unroll
        for (int k = 0; k < 30; ++k) w[k] = W_iC[h*30 + k];
        const float hb = 0.5f * b_iC[h];
        #pragma unroll
        for (int o = 0; o < 8; ++o) {
            const float zc = s_in[o][15];
            const float v0 = s_in[o][0], v1 = s_in[o][1];
            float pj = hb + w[24]*zc + w[26]*v0 + w[27]*v1;
            float pi = hb + w[25]*zc + w[28]*v0 + w[29]*v1;
            #pragma unroll
            for (int k = 0; k < 12; ++k) {
                const float x = s_in[o][2+k];
                pj += w[k]    * x;
                pi += w[12+k] * x;
            }
            proj[o][h]   = pj;
            proj[8+o][h] = pi;
        }
    }
    __syncthreads();
    {
        const int p = tid >> 2, l2 = tid & 3;
        const int ip = p >> 3, jp = p & 7;
        float a = 0.f;
        #pragma unroll
        for (int u = 0; u < 16; ++u) {
            const int h4 = (l2*16 + u) * 4;
            const float4 aj = *(const float4*)&proj[jp][h4];
            const float4 ai = *(const float4*)&proj[8+ip][h4];
            const float4 wv = *(const float4*)&wcc[h4];
            a += wv.x*fmaxf(aj.x+ai.x, 0.f) + wv.y*fmaxf(aj.y+ai.y, 0.f)
               + wv.z*fmaxf(aj.z+ai.z, 0.f) + wv.w*fmaxf(aj.w+ai.w, 0.f);
        }
        a += __shfl_xor(a, 1); a += __shfl_xor(a, 2);
        if (l2 == 0) {
            const float sv = a + consts[1];
            sc_s[p] = sv;
            sC_g[b*64 + jp*8 + ip] = sv;
        }
    }
    __syncthreads();

    // batchnorm partial sums (wave 0)
    if (tid < 64) {
        const float v1 = ss_s[tid], v2 = sc_s[tid];
        float a0 = v1, a1 = v1*v1, a2 = v2, a3 = v2*v2;
        #pragma unroll
        for (int m = 1; m < 64; m <<= 1) {
            a0 += __shfl_xor(a0, m); a1 += __shfl_xor(a1, m);
            a2 += __shfl_xor(a2, m); a3 += __shfl_xor(a3, m);
        }
        if (tid == 0) {
            part_g[b*4 + 0] = a0; part_g[b*4 + 1] = a1;
            part_g[b*4 + 2] = a2; part_g[b*4 + 3] = a3;
        }
    }

    // ---- Ph4a: E projections + pm-weighted accumulation over i (0.5*b_e folded)
    {
        const int h = tid;
        float w[28];
        #pragma unroll
        for (int k = 0; k < 28; ++k) w[k] = W_e[h*28 + k];
        const float hb = 0.5f * b_e[h];
        #pragma unroll
        for (int o = 0; o < 8; ++o) {
            float pj = hb, pi = hb;
            #pragma unroll
            for (int k = 0; k < 14; ++k) {
                const float x = s_in[o][k];
                pj += w[k]    * x;
                pi += w[14+k] * x;
            }
            proj[o][h]   = pj;
            proj[8+o][h] = pi;
        }
    }
    __syncthreads();
    {
        const int h = tid;
        float Pj[8], Pi[8];
        #pragma unroll
        for (int o = 0; o < 8; ++o) { Pj[o] = proj[o][h]; Pi[o] = proj[8+o][h]; }
        #pragma unroll
        for (int j = 0; j < 8; ++j) {
            const float4 pm0 = *(const float4*)&pm_t[j*8];
            const float4 pm1 = *(const float4*)&pm_t[j*8 + 4];
            const float pjv = Pj[j];
            float a = pm0.x*fmaxf(pjv+Pi[0],0.f) + pm0.y*fmaxf(pjv+Pi[1],0.f)
                    + pm0.z*fmaxf(pjv+Pi[2],0.f) + pm0.w*fmaxf(pjv+Pi[3],0.f)
                    + pm1.x*fmaxf(pjv+Pi[4],0.f) + pm1.y*fmaxf(pjv+Pi[5],0.f)
                    + pm1.z*fmaxf(pjv+Pi[6],0.f) + pm1.w*fmaxf(pjv+Pi[7],0.f);
            AccE[j][h] = a;
        }
    }
    __syncthreads();

    // ---- Ph4b: eC projections + mask-weighted accumulation (0.5*b_eC folded)
    {
        const int h = tid;
        float w[30];
        #pragma unroll
        for (int k = 0; k < 30; ++k) w[k] = W_eC[h*30 + k];
        const float hb = 0.5f * b_eC[h];
        #pragma unroll
        for (int o = 0; o < 8; ++o) {
            const float zc = s_in[o][15];
            const float v0 = s_in[o][0], v1 = s_in[o][1];
            float pj = hb + w[24]*zc + w[26]*v0 + w[27]*v1;
            float pi = hb + w[25]*zc + w[28]*v0 + w[29]*v1;
            #pragma unroll
            for (int k = 0; k < 12; ++k) {
                const float x = s_in[o][2+k];
                pj += w[k]    * x;
                pi += w[12+k] * x;
            }
            proj[o][h]   = pj;
            proj[8+o][h] = pi;
        }
    }
    __syncthreads();
    {
        const int h = tid;
        float Pj[8], Pi[8];
        #pragma unroll
        for (int o = 0; o < 8; ++o) { Pj[o] = proj[o][h]; Pi[o] = proj[8+o][h]; }
        #pragma unroll
        for (int j = 0; j < 8; ++j) {
            const float pjv = Pj[j];
            float a = 0.f;
            #pragma unroll
            for (int i = 0; i < 8; ++i)
                a += (i != j) ? fmaxf(pjv + Pi[i], 0.f) : 0.f;
            AccC[j][h] = a;
        }
    }
    __syncthreads();

    // ---- Ph5: y = M2 @ Acc + pmsum*bd ; u = y / max(||y||,1e-12) ----
    {
        const int t = tid >> 3, l3 = tid & 7;   // 32 tasks x 8 lanes
        const int type = t >> 4, c = (t >> 3) & 1, jj = t & 7;
        const float* M2 = type ? m2c : m2m;
        const float (*Acc)[260] = type ? AccC : AccE;
        float a = 0.f;
        #pragma unroll
        for (int u = 0; u < 8; ++u) {
            const int h4 = l3*32 + u*4;
            const float4 mv = *(const float4*)&M2[c*256 + h4];
            const float4 av = *(const float4*)&Acc[jj][h4];
            a += mv.x*av.x + mv.y*av.y + mv.z*av.z + mv.w*av.w;
        }
        a += __shfl_xor(a, 1); a += __shfl_xor(a, 2); a += __shfl_xor(a, 4);
        if (l3 == 0) {
            const float bd = consts[2 + type*2 + c];
            const float pms = type ? 7.0f : pmsum_s[jj];
            y_s[t] = a + pms * bd;
        }
    }
    __syncthreads();
    if (tid < 16) {
        const int type = tid >> 3, j = tid & 7;
        const float y0 = y_s[type*16 + j];
        const float y1 = y_s[type*16 + 8 + j];
        const float n = fmaxf(sqrtf(y0*y0 + y1*y1), 1e-12f);
        float* u = type ? uc_g : um_g;
        u[(b*8 + j)*2 + 0] = y0 / n;
        u[(b*8 + j)*2 + 1] = y1 / n;
    }
}

// ---------------------------------------------------------------------------
// stats: reduce block partials -> kM,cM,kC,cC with normed = s*k + c
// ---------------------------------------------------------------------------
__launch_bounds__(256)
__global__ void stats_kernel(const float* __restrict__ part,
                             const float* __restrict__ gM, const float* __restrict__ beM,
                             const float* __restrict__ gC, const float* __restrict__ beC,
                             float* __restrict__ stats, int nblk, float inv_n)
{
    __shared__ float red[4][4];
    float a0 = 0.f, a1 = 0.f, a2 = 0.f, a3 = 0.f;
    for (int r = threadIdx.x; r < nblk; r += 256) {
        const float4 v = ((const float4*)part)[r];
        a0 += v.x; a1 += v.y; a2 += v.z; a3 += v.w;
    }
    #pragma unroll
    for (int m = 1; m < 64; m <<= 1) {
        a0 += __shfl_xor(a0, m); a1 += __shfl_xor(a1, m);
        a2 += __shfl_xor(a2, m); a3 += __shfl_xor(a3, m);
    }
    const int w = threadIdx.x >> 6;
    if ((threadIdx.x & 63) == 0) {
        red[0][w] = a0; red[1][w] = a1; red[2][w] = a2; red[3][w] = a3;
    }
    __syncthreads();
    if (threadIdx.x == 0) {
        float s = 0.f, s2 = 0.f, sc = 0.f, sc2 = 0.f;
        for (int k = 0; k < 4; ++k) {
            s += red[0][k]; s2 += red[1][k]; sc += red[2][k]; sc2 += red[3][k];
        }
        float mean = s * inv_n;
        float var  = s2 * inv_n - mean*mean;
        float kk   = gM[0] / sqrtf(var + 1e-5f);
        stats[0] = kk;
        stats[1] = beM[0] - mean*kk;
        mean = sc * inv_n;
        var  = sc2 * inv_n - mean*mean;
        kk   = gC[0] / sqrtf(var + 1e-5f);
        stats[2] = kk;
        stats[3] = beC[0] - mean*kk;
    }
}

// ---------------------------------------------------------------------------
// final: scale = sum_i softplus(norm(s))*w ; out = scale*u  (transposed layout:
// s_g/sC_g/pm_g are [token][i] contiguous -> pure float4 reads)
// ---------------------------------------------------------------------------
__launch_bounds__(256)
__global__ void final_kernel(const float* __restrict__ s_g, const float* __restrict__ sC_g,
                             const float* __restrict__ pm_g,
                             const float* __restrict__ um_g, const float* __restrict__ uc_g,
                             const float* __restrict__ stats,
                             float* __restrict__ out, int ntok)
{
    const int t = blockIdx.x * blockDim.x + threadIdx.x;
    if (t >= ntok) return;
    const int j = t & 7;
    const float kM = stats[0], cM = stats[1], kC = stats[2], cC = stats[3];
    const float4 sa = *(const float4*)&s_g[t*8];
    const float4 sb = *(const float4*)&s_g[t*8 + 4];
    const float4 ca = *(const float4*)&sC_g[t*8];
    const float4 cb = *(const float4*)&sC_g[t*8 + 4];
    const float4 pa = *(const float4*)&pm_g[t*8];
    const float4 pb = *(const float4*)&pm_g[t*8 + 4];
    const float sv[8] = {sa.x,sa.y,sa.z,sa.w, sb.x,sb.y,sb.z,sb.w};
    const float cv[8] = {ca.x,ca.y,ca.z,ca.w, cb.x,cb.y,cb.z,cb.w};
    const float pv[8] = {pa.x,pa.y,pa.z,pa.w, pb.x,pb.y,pb.z,pb.w};
    float sc = 0.f, scC = 0.f, spj = 0.f;
    #pragma unroll
    for (int i = 0; i < 8; ++i) {
        const float sn = sv[i]*kM + cM;
        const float sp = fmaxf(sn, 0.f) + log1pf(expf(-fabsf(sn)));
        sc += sp * pv[i];
        const float snc = cv[i]*kC + cC;
        const float spc = fmaxf(snc, 0.f) + log1pf(expf(-fabsf(snc)));
        scC += spc;
        if (i == j) spj = spc;
    }
    scC -= spj;
    const float2 u_m = *(const float2*)&um_g[t*2];
    const float2 u_c = *(const float2*)&uc_g[t*2];
    const float m0 = sc  * u_m.x, m1 = sc  * u_m.y;
    const float c0 = scC * u_c.x, c1 = scC * u_c.y;
    *(float2*)&out[t*2]          = make_float2(m0 + c0, m1 + c1);
    *(float2*)&out[ntok*2 + t*2] = make_float2(m0, m1);
    *(float2*)&out[ntok*4 + t*2] = make_float2(c0, c1);
}

extern "C" void kernel_launch(void* const* d_in, const int* in_sizes, int n_in,
                              void* d_out, int out_size, void* d_ws, size_t ws_size,
                              hipStream_t stream) {
    const float* z_dyn    = (const float*)d_in[0];
    const float* z_contex = (const float*)d_in[1];
    const float* z_mc     = (const float*)d_in[2];
    const float* W_e   = (const float*)d_in[3];  const float* b_e   = (const float*)d_in[4];
    const float* W_i   = (const float*)d_in[5];  const float* b_i   = (const float*)d_in[6];
    const float* W_a   = (const float*)d_in[7];  const float* b_a   = (const float*)d_in[8];
    const float* W_2   = (const float*)d_in[9];  const float* b_2   = (const float*)d_in[10];
    const float* W_at  = (const float*)d_in[11]; const float* b_at  = (const float*)d_in[12];
    const float* W_at2 = (const float*)d_in[13]; const float* b_at2 = (const float*)d_in[14];
    const float* W_s1  = (const float*)d_in[15]; const float* b_s1  = (const float*)d_in[16];
    const float* W_s2  = (const float*)d_in[17]; const float* b_s2  = (const float*)d_in[18];
    const float* W_eC  = (const float*)d_in[19]; const float* b_eC  = (const float*)d_in[20];
    const float* W_iC  = (const float*)d_in[21]; const float* b_iC  = (const float*)d_in[22];
    const float* W_2C  = (const float*)d_in[23]; const float* b_2C  = (const float*)d_in[24];
    const float* W_s1C = (const float*)d_in[25]; const float* b_s1C = (const float*)d_in[26];
    const float* W_s2C = (const float*)d_in[27]; const float* b_s2C = (const float*)d_in[28];
    const float* g_M   = (const float*)d_in[29]; const float* be_M  = (const float*)d_in[30];
    const float* g_C   = (const float*)d_in[31]; const float* be_C  = (const float*)d_in[32];
    const float* W_d   = (const float*)d_in[33];
    const float* W_dC  = (const float*)d_in[34];

    const int ntok = in_sizes[0] / 2;   // 16384
    const int B = ntok / 8;             // 2048

    float* ws = (float*)d_ws;
    float* pm_g   = ws;                  // B*64 (transposed: [b][j][i])
    float* s_g    = pm_g + B*64;         // B*64 (transposed)
    float* sC_g   = s_g  + B*64;         // B*64 (transposed)
    float* um_g   = sC_g + B*64;         // ntok*2
    float* uc_g   = um_g + ntok*2;       // ntok*2
    float* part_g = uc_g + ntok*2;       // B*4
    float* wcm    = part_g + B*4;        // 256
    float* wcc    = wcm + 256;           // 256
    float* m2m    = wcc + 256;           // 512
    float* m2c    = m2m + 512;           // 512
    float* consts = m2c + 512;           // 8
    float* stats  = consts + 8;          // 4
    unsigned short* Wh = (unsigned short*)(stats + 4);   // NPAD*HDIM bf16 bits
    unsigned short* Wl = Wh + NPAD*HDIM;

    prep_kernel<<<14, 256, 0, stream>>>(
        W_s1, b_s1, W_s2, b_s2, W_s1C, b_s1C, W_s2C, b_s2C,
        W_2, b_2, W_d, W_2C, b_2C, W_dC, W_at,
        wcm, wcc, m2m, m2c, consts, Wh, Wl);

    main_kernel<<<B, 256, 0, stream>>>(
        z_dyn, z_contex, z_mc,
        W_e, b_e, W_i, b_i, W_a, b_a, b_at, W_at2, b_at2,
        W_eC, b_eC, W_iC, b_iC,
        Wh, Wl,
        wcm, wcc, m2m, m2c, consts,
        pm_g, s_g, sC_g, um_g, uc_g, part_g);

    stats_kernel<<<1, 256, 0, stream>>>(
        part_g, g_M, be_M, g_C, be_C, stats, B, 1.0f / (float)(B*64));

    final_kernel<<<(ntok + 255)/256, 256, 0, stream>>>(
        s_g, sC_g, pm_g, um_g, uc_g, stats, (float*)d_out, ntok);
}